// Round 1
// baseline (407.075 us; speedup 1.0000x reference)
//
#include <hip/hip_runtime.h>

// ---------------------------------------------------------------------------
// GraphVAELoss: A_recon (stream 268MB, memory-bound) + KL_A (tiny) +
// KL_i (two small einsums + KL, 67MB + 537M MACs) + finalize.
// Partials go to deterministic ws slots (doubles); no contended atomics.
// ws layout (doubles): [0,2048) arecon block partials
//                      [2048,3072) kli block partials
//                      [3072,3104) kla per-b values
// ---------------------------------------------------------------------------

static constexpr int BB = 32;
static constexpr int NN = 1024;
static constexpr int ZIc = 64;
static constexpr int ZAc = 128;
static constexpr int NV4 = (BB * NN * NN) / 4;   // 8,388,608 float4s
static constexpr int ABLOCKS = 2048;

#define EPSV 1e-10f
#define SPW 0.7f

__device__ __forceinline__ float ll_elem(float a, float t) {
    // faithful: clamp 0->EPS, 1->1-EPS; ll = t*log(a)+(1-t)*log(1-a);
    // where t==0: ll *= 0.7
    a = (a == 0.0f) ? EPSV : ((a == 1.0f) ? (1.0f - EPSV) : a);
    float la  = __logf(a);
    float l1a = __logf(1.0f - a);
    float v = t * la + (1.0f - t) * l1a;
    return (t == 0.0f) ? SPW * v : v;
}

__global__ __launch_bounds__(256) void arecon_kernel(
        const float4* __restrict__ Ah, const float4* __restrict__ At,
        double* __restrict__ slots) {
    float lsum = 0.0f;
    const int stride = gridDim.x * blockDim.x;
    for (int i = blockIdx.x * blockDim.x + threadIdx.x; i < NV4; i += stride) {
        float4 a = Ah[i];
        float4 t = At[i];
        lsum += ll_elem(a.x, t.x);
        lsum += ll_elem(a.y, t.y);
        lsum += ll_elem(a.z, t.z);
        lsum += ll_elem(a.w, t.w);
    }
#pragma unroll
    for (int m = 1; m < 64; m <<= 1) lsum += __shfl_xor(lsum, m, 64);
    __shared__ float wsum[4];
    const int lane = threadIdx.x & 63, wv = threadIdx.x >> 6;
    if (lane == 0) wsum[wv] = lsum;
    __syncthreads();
    if (threadIdx.x == 0)
        slots[blockIdx.x] = (double)(wsum[0] + wsum[1] + wsum[2] + wsum[3]);
}

// One block per node n (1024 blocks, 256 threads = 4 waves).
// Wave w handles b = {w, 4+w, ..., 28+w}; lane f in [0,64) owns feature row f.
// B rows are loaded in 16-float register chunks, reused across all 8 b's.
// z_a addresses are wave-uniform -> scalar loads.
__global__ __launch_bounds__(256) void kli_kernel(
        const float* __restrict__ mu_i, const float* __restrict__ lv_i,
        const float* __restrict__ z_a,
        const float* __restrict__ Bmu, const float* __restrict__ Blv,
        double* __restrict__ slots) {
    const int n    = blockIdx.x;
    const int wave = threadIdx.x >> 6;
    const int f    = threadIdx.x & 63;

    const float4* bmu = reinterpret_cast<const float4*>(Bmu + ((size_t)n * ZIc + f) * ZAc);
    const float4* blv = reinterpret_cast<const float4*>(Blv + ((size_t)n * ZIc + f) * ZAc);

    float pm[8], pl[8];
#pragma unroll
    for (int i = 0; i < 8; ++i) { pm[i] = 0.0f; pl[i] = 0.0f; }

    for (int c = 0; c < 8; ++c) {          // 8 chunks of 16 g-values
        float4 m[4], l[4];
#pragma unroll
        for (int q = 0; q < 4; ++q) { m[q] = bmu[c * 4 + q]; l[q] = blv[c * 4 + q]; }
#pragma unroll
        for (int bi = 0; bi < 8; ++bi) {
            const int b = bi * 4 + wave;
            const float* z = z_a + b * ZAc + c * 16;
#pragma unroll
            for (int q = 0; q < 4; ++q) {
                float4 zz = *reinterpret_cast<const float4*>(z + q * 4);  // uniform
                pm[bi] += m[q].x * zz.x + m[q].y * zz.y + m[q].z * zz.z + m[q].w * zz.w;
                pl[bi] += l[q].x * zz.x + l[q].y * zz.y + l[q].z * zz.z + l[q].w * zz.w;
            }
        }
    }

    double local = 0.0;
#pragma unroll
    for (int bi = 0; bi < 8; ++bi) {
        const int b = bi * 4 + wave;
        const size_t base = ((size_t)b * NN + n) * ZIc + f;
        float m1  = mu_i[base];
        float lv1 = lv_i[base];
        float d   = lv1 - pl[bi];              // contributes to log-det ratio
        float tr  = __expf(d);                 // trace term element
        float dm  = pm[bi] - m1;
        float inn = dm * dm * __expf(-pl[bi]); // inner-product term element
        float sd = d, st = tr, si = inn;
#pragma unroll
        for (int m = 1; m < 64; m <<= 1) {
            sd += __shfl_xor(sd, m, 64);
            st += __shfl_xor(st, m, 64);
            si += __shfl_xor(si, m, 64);
        }
        if (f == 0)
            local += (double)(0.5f * __expf(sd) - 64.0f + st + si);
    }
    // combine 4 waves' partials via LDS, one slot write per block
    __shared__ double wacc[4];
    if (f == 0) wacc[wave] = local;
    __syncthreads();
    if (threadIdx.x == 0)
        slots[n] = wacc[0] + wacc[1] + wacc[2] + wacc[3];
}

__global__ __launch_bounds__(64) void kla_kernel(
        const float* __restrict__ mu_A, const float* __restrict__ lv_A,
        double* __restrict__ slots) {
    const int b = blockIdx.x;
    const int lane = threadIdx.x;
    float lv0 = lv_A[b * ZAc + lane], lv1 = lv_A[b * ZAc + 64 + lane];
    float m0  = mu_A[b * ZAc + lane], m1  = mu_A[b * ZAc + 64 + lane];
    float slv = lv0 + lv1;
    float str = __expf(lv0) + __expf(lv1);
    float sin_ = m0 * m0 + m1 * m1;
#pragma unroll
    for (int m = 1; m < 64; m <<= 1) {
        slv  += __shfl_xor(slv, m, 64);
        str  += __shfl_xor(str, m, 64);
        sin_ += __shfl_xor(sin_, m, 64);
    }
    if (lane == 0)
        slots[b] = (double)(0.5f * __expf(slv) - 128.0f + str + sin_);
}

__global__ __launch_bounds__(256) void finalize_kernel(
        const double* __restrict__ ws, float* __restrict__ out) {
    double a = 0.0, ki = 0.0, ka = 0.0;
    for (int i = threadIdx.x; i < ABLOCKS; i += 256) a  += ws[i];
    for (int i = threadIdx.x; i < 1024;    i += 256) ki += ws[ABLOCKS + i];
    if (threadIdx.x < 32) ka = ws[ABLOCKS + 1024 + threadIdx.x];
#pragma unroll
    for (int m = 1; m < 64; m <<= 1) {
        a  += __shfl_xor(a, m, 64);
        ki += __shfl_xor(ki, m, 64);
        ka += __shfl_xor(ka, m, 64);
    }
    __shared__ double sa[4], ski[4], ska[4];
    const int lane = threadIdx.x & 63, wv = threadIdx.x >> 6;
    if (lane == 0) { sa[wv] = a; ski[wv] = ki; ska[wv] = ka; }
    __syncthreads();
    if (threadIdx.x == 0) {
        double A  = (sa[0] + sa[1] + sa[2] + sa[3]) / 32.0;
        double KI = (ski[0] + ski[1] + ski[2] + ski[3]) / 32.0;
        double KA = (ska[0] + ska[1] + ska[2] + ska[3]) / 32.0;
        out[0] = (float)A;
        out[1] = (float)KA;
        out[2] = (float)KI;
        out[3] = (float)(-(A + KA + KI));
    }
}

extern "C" void kernel_launch(void* const* d_in, const int* in_sizes, int n_in,
                              void* d_out, int out_size, void* d_ws, size_t ws_size,
                              hipStream_t stream) {
    const float* Ah   = (const float*)d_in[0];   // A_hat_batch  [32,1024,1024]
    const float* At   = (const float*)d_in[1];   // A_true       [32,1024,1024]
    const float* mu_A = (const float*)d_in[4];   // [32,128]
    const float* lv_A = (const float*)d_in[5];   // [32,128]
    const float* mu_i = (const float*)d_in[6];   // [32,1024,64]
    const float* lv_i = (const float*)d_in[7];   // [32,1024,64]
    const float* z_a  = (const float*)d_in[8];   // [32,128]
    const float* Bmu  = (const float*)d_in[9];   // [1024,64,128]
    const float* Blv  = (const float*)d_in[10];  // [1024,64,128]

    double* ws = (double*)d_ws;   // 3104 doubles = 24.25 KB, all slots written every call
    float* out = (float*)d_out;

    hipLaunchKernelGGL(arecon_kernel, dim3(ABLOCKS), dim3(256), 0, stream,
                       (const float4*)Ah, (const float4*)At, ws);
    hipLaunchKernelGGL(kli_kernel, dim3(1024), dim3(256), 0, stream,
                       mu_i, lv_i, z_a, Bmu, Blv, ws + ABLOCKS);
    hipLaunchKernelGGL(kla_kernel, dim3(32), dim3(64), 0, stream,
                       mu_A, lv_A, ws + ABLOCKS + 1024);
    hipLaunchKernelGGL(finalize_kernel, dim3(1), dim3(256), 0, stream, ws, out);
}